// Round 1
// baseline (482.122 us; speedup 1.0000x reference)
//
#include <hip/hip_runtime.h>

#define M_TOT 16384
#define N_TOT 2048
#define K_TOT 2048
#define RANK  8

typedef __bf16 bf16x8 __attribute__((ext_vector_type(8)));
typedef float  f32x4  __attribute__((ext_vector_type(4)));

__device__ __forceinline__ unsigned short f2bf(float f) {
    union { float f; unsigned u; } v; v.f = f;
    unsigned u = v.u;
    u += 0x7fffu + ((u >> 16) & 1u);   // round-to-nearest-even
    return (unsigned short)(u >> 16);
}

// ---------------------------------------------------------------- conv_x ----
// x fp32 [16384][2048] -> bf16, vectorized (float4 in, ushort4 out).
__global__ __launch_bounds__(256) void conv_x_kernel(const float* __restrict__ x,
                                                     unsigned short* __restrict__ xb) {
    const long long n = (long long)M_TOT * K_TOT;
    long long i = ((long long)blockIdx.x * 256 + threadIdx.x) * 4;
    const long long stride = (long long)gridDim.x * 256 * 4;
    for (; i < n; i += stride) {
        const float4 v = *reinterpret_cast<const float4*>(x + i);
        ushort4 o;
        o.x = f2bf(v.x); o.y = f2bf(v.y); o.z = f2bf(v.z); o.w = f2bf(v.w);
        *reinterpret_cast<ushort4*>(xb + i) = o;
    }
}

// ---------------------------------------------------------------- prep_w ----
// Wt[e][d] = sum_r F[r][d][e], bf16 output (transposed so GEMM B-frags are
// contiguous in LDS). 64x64 tile per block, register accumulate over r,
// transpose via padded LDS tile (pad 65 -> 2-way bank alias = free).
__global__ __launch_bounds__(256) void prep_w_kernel(const float* __restrict__ F,
                                                     unsigned short* __restrict__ wt) {
    __shared__ float tile[64][65];
    const int bx = blockIdx.x & 31;   // d tile
    const int by = blockIdx.x >> 5;   // e tile
    const int d0 = bx << 6;
    const int e0 = by << 6;
    const int t  = threadIdx.x;
    const int dl = t >> 4;            // 0..15
    const int e4 = (t & 15) << 2;     // 0..60

    float4 acc[4];
#pragma unroll
    for (int q = 0; q < 4; ++q) acc[q] = make_float4(0.f, 0.f, 0.f, 0.f);

    for (int r = 0; r < RANK; ++r) {
        const float* Fr = F + (size_t)r * K_TOT * N_TOT;
#pragma unroll
        for (int q = 0; q < 4; ++q) {
            const int d = d0 + (q << 4) + dl;
            const float4 v = *reinterpret_cast<const float4*>(Fr + (size_t)d * N_TOT + e0 + e4);
            acc[q].x += v.x; acc[q].y += v.y; acc[q].z += v.z; acc[q].w += v.w;
        }
    }
#pragma unroll
    for (int q = 0; q < 4; ++q) {
        const int d = (q << 4) + dl;
        tile[d][e4 + 0] = acc[q].x;
        tile[d][e4 + 1] = acc[q].y;
        tile[d][e4 + 2] = acc[q].z;
        tile[d][e4 + 3] = acc[q].w;
    }
    __syncthreads();
#pragma unroll
    for (int p = 0; p < 4; ++p) {
        const int el = (p << 4) + (t >> 4);
        const int dg = (t & 15) << 2;
        ushort4 o;
        o.x = f2bf(tile[dg + 0][el]);
        o.y = f2bf(tile[dg + 1][el]);
        o.z = f2bf(tile[dg + 2][el]);
        o.w = f2bf(tile[dg + 3][el]);
        *reinterpret_cast<ushort4*>(wt + (size_t)(e0 + el) * K_TOT + d0 + dg) = o;
    }
}

// ------------------------------------------------------------------ gemm ----
// C = (Xb @ Wsum) * scale + bias.  Xb bf16 [M][K], Wt bf16 [N][K] (= Wsum^T).
// m97 structure: 128x128 tile, BK=32, 4 waves (2x2), global_load_lds width 16,
// mfma_f32_16x16x32_bf16 with 4x4 fragments per wave.
__global__ __launch_bounds__(256, 2) void gemm_kernel(const unsigned short* __restrict__ xb,
                                                      const unsigned short* __restrict__ wt,
                                                      const float* __restrict__ bias,
                                                      float* __restrict__ out) {
    __shared__ __align__(16) unsigned short As[128 * 32];
    __shared__ __align__(16) unsigned short Bs[128 * 32];

    // XCD-aware bijective swizzle (nwg = 2048, divisible by 8)
    const int nwg = gridDim.x;
    int bid = blockIdx.x;
    bid = (bid & 7) * (nwg >> 3) + (bid >> 3);
    const int tn = bid & 15;               // N_TOT/128 = 16
    const int tm = bid >> 4;
    const int row0 = tm << 7;
    const int col0 = tn << 7;

    const int t    = threadIdx.x;
    const int lane = t & 63;
    const int wave = t >> 6;
    const int wr   = (wave >> 1) << 6;     // wave row offset 0/64
    const int wc   = (wave & 1) << 6;      // wave col offset 0/64

    const int srow  = t >> 2;              // staging row 0..63 (+64 for q=1)
    const int scolb = (t & 3) << 4;        // staging byte within 64-B row

    const int fr  = lane & 15;             // frag row (A) / col (B)
    const int fkb = (lane >> 4) << 4;      // byte offset of 8-elem k slice

    f32x4 acc[4][4] = {};

    const char* gA = (const char*)(xb + (size_t)row0 * K_TOT);
    const char* gB = (const char*)(wt + (size_t)col0 * K_TOT);
    char* ldsA = (char*)As + (size_t)wave * 1024;   // wave-uniform LDS base
    char* ldsB = (char*)Bs + (size_t)wave * 1024;

    for (int k0 = 0; k0 < K_TOT; k0 += 32) {
        __syncthreads();
        const size_t kb = (size_t)k0 * 2;
        __builtin_amdgcn_global_load_lds(
            (const __attribute__((address_space(1))) void*)(gA + (size_t)srow * (K_TOT * 2) + kb + scolb),
            (__attribute__((address_space(3))) void*)ldsA, 16, 0, 0);
        __builtin_amdgcn_global_load_lds(
            (const __attribute__((address_space(1))) void*)(gA + (size_t)(srow + 64) * (K_TOT * 2) + kb + scolb),
            (__attribute__((address_space(3))) void*)(ldsA + 4096), 16, 0, 0);
        __builtin_amdgcn_global_load_lds(
            (const __attribute__((address_space(1))) void*)(gB + (size_t)srow * (K_TOT * 2) + kb + scolb),
            (__attribute__((address_space(3))) void*)ldsB, 16, 0, 0);
        __builtin_amdgcn_global_load_lds(
            (const __attribute__((address_space(1))) void*)(gB + (size_t)(srow + 64) * (K_TOT * 2) + kb + scolb),
            (__attribute__((address_space(3))) void*)(ldsB + 4096), 16, 0, 0);
        __syncthreads();

        bf16x8 af[4], bv[4];
#pragma unroll
        for (int m = 0; m < 4; ++m)
            af[m] = *reinterpret_cast<const bf16x8*>((const char*)As + (wr + m * 16 + fr) * 64 + fkb);
#pragma unroll
        for (int n = 0; n < 4; ++n)
            bv[n] = *reinterpret_cast<const bf16x8*>((const char*)Bs + (wc + n * 16 + fr) * 64 + fkb);
#pragma unroll
        for (int m = 0; m < 4; ++m)
#pragma unroll
            for (int n = 0; n < 4; ++n)
                acc[m][n] = __builtin_amdgcn_mfma_f32_16x16x32_bf16(af[m], bv[n], acc[m][n], 0, 0, 0);
    }

    // Epilogue: C/D layout col = lane&15, row = (lane>>4)*4 + reg  [m89-verified]
    const float scale = 0.35355339059327373f;  // 1/sqrt(8)
    const int rgrp = (lane >> 4) << 2;
#pragma unroll
    for (int n = 0; n < 4; ++n) {
        const int col = col0 + wc + n * 16 + fr;
        const float bvv = bias[col];
#pragma unroll
        for (int m = 0; m < 4; ++m) {
            const int rbase = row0 + wr + m * 16 + rgrp;
#pragma unroll
            for (int i = 0; i < 4; ++i)
                out[(size_t)(rbase + i) * N_TOT + col] = acc[m][n][i] * scale + bvv;
        }
    }
}

// ----------------------------------------------------------------- naive ----
// Fallback if ws is too small: correct but slow.
__global__ __launch_bounds__(256) void naive_kernel(const float* __restrict__ x,
                                                    const float* __restrict__ F,
                                                    const float* __restrict__ bias,
                                                    float* __restrict__ out) {
    const int m = blockIdx.x;
    __shared__ float xs[K_TOT];
    for (int i = threadIdx.x; i < K_TOT; i += 256) xs[i] = x[(size_t)m * K_TOT + i];
    __syncthreads();
    for (int e = threadIdx.x; e < N_TOT; e += 256) {
        float acc = 0.f;
        for (int r = 0; r < RANK; ++r) {
            const float* Fr = F + (size_t)r * K_TOT * N_TOT;
            float s = 0.f;
            for (int d = 0; d < K_TOT; ++d) s += xs[d] * Fr[(size_t)d * N_TOT + e];
            acc += s;
        }
        out[(size_t)m * N_TOT + e] = acc * 0.35355339059327373f + bias[e];
    }
}

extern "C" void kernel_launch(void* const* d_in, const int* in_sizes, int n_in,
                              void* d_out, int out_size, void* d_ws, size_t ws_size,
                              hipStream_t stream) {
    const float* x    = (const float*)d_in[0];
    const float* F    = (const float*)d_in[1];
    const float* bias = (const float*)d_in[2];
    float* out        = (float*)d_out;

    const size_t xb_bytes = (size_t)M_TOT * K_TOT * 2;   // 64 MiB
    const size_t wt_bytes = (size_t)N_TOT * K_TOT * 2;   //  8 MiB

    if (ws_size >= xb_bytes + wt_bytes) {
        unsigned short* xb = (unsigned short*)d_ws;
        unsigned short* wt = (unsigned short*)((char*)d_ws + xb_bytes);
        conv_x_kernel<<<dim3(2048), dim3(256), 0, stream>>>(x, xb);
        prep_w_kernel<<<dim3(1024), dim3(256), 0, stream>>>(F, wt);
        gemm_kernel<<<dim3(2048), dim3(256), 0, stream>>>(xb, wt, bias, out);
    } else {
        naive_kernel<<<dim3(M_TOT), dim3(256), 0, stream>>>(x, F, bias, out);
    }
}